// Round 1
// baseline (597.140 us; speedup 1.0000x reference)
//
#include <hip/hip_runtime.h>
#include <hip/hip_bf16.h>
#include <math.h>

// Problem constants (from reference)
#define LSEQ 12544      // H*W = 112*112
#define NB   2          // batch
#define DM   128        // d_model
#define DI   256        // d_inner
#define DS   16         // d_state
#define RNK  8          // dt_rank
#define NTOK (NB*LSEQ)  // 25088 tokens
#define CCH  256        // scan chunks
#define TCH  49         // tokens per chunk (256*49 = 12544)

__device__ __forceinline__ float sigmoidf_(float x){ return 1.f/(1.f+__expf(-x)); }

// C[M,N] = (A (+A2)) [M,K] @ W[N,K]^T   (all fp32, row-major; M%64==0, N%64==0, K%32==0)
template<int BM,int BN,int BK>
__global__ __launch_bounds__(256)
void gemm_tn(const float* __restrict__ A, const float* __restrict__ A2,
             const float* __restrict__ W, float* __restrict__ C,
             int M, int N, int K)
{
    __shared__ float As[BK][BM+4];
    __shared__ float Ws[BK][BN+4];
    const int tid = threadIdx.x;
    const int tx = tid & 15, ty = tid >> 4;
    const int m0 = blockIdx.x * BM, n0 = blockIdx.y * BN;
    float acc[4][4] = {};
    for (int k0 = 0; k0 < K; k0 += BK) {
        #pragma unroll
        for (int pass = 0; pass < 2; ++pass) {
            int r  = (tid >> 3) + pass*32;
            int c4 = (tid & 7) * 4;
            float4 v = *(const float4*)&A[(size_t)(m0+r)*K + k0 + c4];
            if (A2) {
                float4 v2 = *(const float4*)&A2[(size_t)(m0+r)*K + k0 + c4];
                v.x+=v2.x; v.y+=v2.y; v.z+=v2.z; v.w+=v2.w;
            }
            As[c4+0][r]=v.x; As[c4+1][r]=v.y; As[c4+2][r]=v.z; As[c4+3][r]=v.w;
            float4 w = *(const float4*)&W[(size_t)(n0+r)*K + k0 + c4];
            Ws[c4+0][r]=w.x; Ws[c4+1][r]=w.y; Ws[c4+2][r]=w.z; Ws[c4+3][r]=w.w;
        }
        __syncthreads();
        #pragma unroll
        for (int kk = 0; kk < BK; ++kk) {
            float4 a = *(const float4*)&As[kk][ty*4];
            float4 b = *(const float4*)&Ws[kk][tx*4];
            float av[4]={a.x,a.y,a.z,a.w}, bv[4]={b.x,b.y,b.z,b.w};
            #pragma unroll
            for (int i=0;i<4;i++)
                #pragma unroll
                for (int j=0;j<4;j++)
                    acc[i][j] += av[i]*bv[j];
        }
        __syncthreads();
    }
    #pragma unroll
    for (int i=0;i<4;i++)
        #pragma unroll
        for (int j=0;j<4;j++)
            C[(size_t)(m0+ty*4+i)*N + n0 + tx*4 + j] = acc[i][j];
}

// Per (dir,b,32-token tile): causal depthwise conv + silu -> xcf; xcf@x_w.T -> (dtr,B,C);
// softplus(dtr@dt_w.T + dt_b) -> dt
__global__ __launch_bounds__(256)
void conv_proj(const float* __restrict__ xz,
               const float* __restrict__ conv_w, const float* __restrict__ conv_b,
               const float* __restrict__ x_w,
               const float* __restrict__ dt_w, const float* __restrict__ dt_b,
               float* __restrict__ xcf, float* __restrict__ dtv, float* __restrict__ bc)
{
    const int TB = 32;
    __shared__ float xs[TB][DI+4];   // post-silu conv output tile
    __shared__ float dtr[TB][RNK];
    const int d  = threadIdx.x;
    const int p0 = blockIdx.x * TB;
    const int b  = blockIdx.y, dir = blockIdx.z;
    const float* xzb = xz + (size_t)b * LSEQ * 512;
    const size_t obase = ((size_t)(dir*NB + b)) * LSEQ;

    const float w0 = conv_w[d*4+0], w1 = conv_w[d*4+1], w2 = conv_w[d*4+2], w3 = conv_w[d*4+3];
    const float cb = conv_b[d];
    for (int t = 0; t < TB; ++t) {
        const int p = p0 + t;
        float acc = cb;
        #pragma unroll
        for (int k = 0; k < 4; ++k) {
            const int pin = (dir == 0) ? (p - 3 + k) : (p + 3 - k);
            const float wk = (k==0)?w0:(k==1)?w1:(k==2)?w2:w3;
            float xv = (pin >= 0 && pin < LSEQ) ? xzb[(size_t)pin*512 + d] : 0.f;
            acc += wk * xv;
        }
        const float s = acc * sigmoidf_(acc);       // silu
        xs[t][d] = s;
        xcf[(obase + p)*DI + d] = s;
    }
    __syncthreads();
    // x-proj: 40 outputs x 32 tokens = 1280 dot-products of length 256
    #pragma unroll
    for (int it = 0; it < 5; ++it) {
        const int idx = it*256 + d;
        const int t = idx / 40, o = idx % 40;
        const float* wr = x_w + o*DI;
        float acc = 0.f;
        for (int k = 0; k < DI; k += 4) {
            float4 xv = *(const float4*)&xs[t][k];
            float4 wv = *(const float4*)&wr[k];
            acc += xv.x*wv.x + xv.y*wv.y + xv.z*wv.z + xv.w*wv.w;
        }
        if (o < RNK) dtr[t][o] = acc;
        else         bc[(obase + p0 + t)*32 + (o - RNK)] = acc;
    }
    __syncthreads();
    // dt-proj + softplus
    float dw[RNK];
    #pragma unroll
    for (int j=0;j<RNK;j++) dw[j] = dt_w[d*RNK+j];
    const float db = dt_b[d];
    for (int t = 0; t < TB; ++t) {
        float acc = db;
        #pragma unroll
        for (int j=0;j<RNK;j++) acc += dtr[t][j]*dw[j];
        const float sp = (acc > 20.f) ? acc : log1pf(__expf(acc));
        dtv[(obase + p0 + t)*DI + d] = sp;
    }
}

// Phase 1: per-chunk local scan (h0=0) + cumulative decay
__global__ __launch_bounds__(256)
void scan_phase1(const float* __restrict__ dtv, const float* __restrict__ xcf,
                 const float* __restrict__ bc, const float* __restrict__ A_log,
                 float* __restrict__ Pg, float* __restrict__ Hg)
{
    const int d = threadIdx.x;
    const int c = blockIdx.x, b = blockIdx.y, dir = blockIdx.z;
    float a2[DS];
    #pragma unroll
    for (int n=0;n<DS;n++) a2[n] = -__expf(A_log[d*DS+n]) * 1.4426950408889634f;
    float h[DS];
    #pragma unroll
    for (int n=0;n<DS;n++) h[n]=0.f;
    float dtsum = 0.f;
    const size_t base = ((size_t)(dir*NB + b)) * LSEQ;
    for (int t = 0; t < TCH; ++t) {
        const int l = c*TCH + t;
        const int p = (dir==0) ? l : (LSEQ-1-l);
        const float dt = dtv[(base+p)*DI + d];
        const float xv = xcf[(base+p)*DI + d];
        const float4* bp = (const float4*)(bc + (base+p)*32);
        const float4 B0=bp[0],B1=bp[1],B2=bp[2],B3=bp[3];
        const float Bv[16]={B0.x,B0.y,B0.z,B0.w,B1.x,B1.y,B1.z,B1.w,
                            B2.x,B2.y,B2.z,B2.w,B3.x,B3.y,B3.z,B3.w};
        const float u = dt * xv;
        dtsum += dt;
        #pragma unroll
        for (int n=0;n<DS;n++) {
            const float dA = exp2f(dt * a2[n]);
            h[n] = dA*h[n] + u*Bv[n];
        }
    }
    const size_t o = ((size_t)((dir*NB + b)*CCH + c))*(DI*DS) + d*DS;
    #pragma unroll
    for (int n=0;n<DS;n++) { Pg[o+n] = exp2f(dtsum * a2[n]); Hg[o+n] = h[n]; }
}

// Phase 2: sequential combine across chunks (one thread per (dir,b,d,n))
__global__ __launch_bounds__(256)
void scan_combine(const float* __restrict__ Pg, const float* __restrict__ Hg,
                  float* __restrict__ H0)
{
    const int tid = blockIdx.x*blockDim.x + threadIdx.x;  // 16384 threads
    const int dn = tid & 4095;
    const int g  = tid >> 12;            // dir*2+b
    float h = 0.f;
    for (int c = 0; c < CCH; ++c) {
        const size_t o = ((size_t)(g*CCH + c))*(DI*DS) + dn;
        H0[o] = h;
        h = Pg[o]*h + Hg[o];
    }
}

// Phase 3: re-scan with correct initial state, emit gated y
__global__ __launch_bounds__(256)
void scan_phase3(const float* __restrict__ dtv, const float* __restrict__ xcf,
                 const float* __restrict__ bc, const float* __restrict__ A_log,
                 const float* __restrict__ H0, const float* __restrict__ xz,
                 const float* __restrict__ Dw, float* __restrict__ yg)
{
    const int d = threadIdx.x;
    const int c = blockIdx.x, b = blockIdx.y, dir = blockIdx.z;
    float a2[DS];
    #pragma unroll
    for (int n=0;n<DS;n++) a2[n] = -__expf(A_log[d*DS+n]) * 1.4426950408889634f;
    float h[DS];
    const size_t ho = ((size_t)((dir*NB + b)*CCH + c))*(DI*DS) + d*DS;
    #pragma unroll
    for (int n=0;n<DS;n++) h[n] = H0[ho+n];
    const float Dv = Dw[d];
    const size_t base = ((size_t)(dir*NB + b)) * LSEQ;
    const size_t zb   = (size_t)b * LSEQ;
    for (int t = 0; t < TCH; ++t) {
        const int l = c*TCH + t;
        const int p = (dir==0) ? l : (LSEQ-1-l);
        const float dt = dtv[(base+p)*DI + d];
        const float xv = xcf[(base+p)*DI + d];
        const float4* bp = (const float4*)(bc + (base+p)*32);
        const float4 B0=bp[0],B1=bp[1],B2=bp[2],B3=bp[3];
        const float4 C0=bp[4],C1=bp[5],C2=bp[6],C3=bp[7];
        const float Bv[16]={B0.x,B0.y,B0.z,B0.w,B1.x,B1.y,B1.z,B1.w,
                            B2.x,B2.y,B2.z,B2.w,B3.x,B3.y,B3.z,B3.w};
        const float Cv[16]={C0.x,C0.y,C0.z,C0.w,C1.x,C1.y,C1.z,C1.w,
                            C2.x,C2.y,C2.z,C2.w,C3.x,C3.y,C3.z,C3.w};
        const float u = dt*xv;
        float y = 0.f;
        #pragma unroll
        for (int n=0;n<DS;n++){
            const float dA = exp2f(dt*a2[n]);
            h[n] = dA*h[n] + u*Bv[n];
            y += h[n]*Cv[n];
        }
        const float z = xz[(zb+p)*512 + DI + d];
        yg[(base+p)*DI + d] = (y + xv*Dv) * (z * sigmoidf_(z));
    }
}

extern "C" void kernel_launch(void* const* d_in, const int* in_sizes, int n_in,
                              void* d_out, int out_size, void* d_ws, size_t ws_size,
                              hipStream_t stream)
{
    const float* x      = (const float*)d_in[0];
    const float* in_w   = (const float*)d_in[1];
    const float* conv_w = (const float*)d_in[2];
    const float* conv_b = (const float*)d_in[3];
    const float* x_w    = (const float*)d_in[4];
    const float* dt_w   = (const float*)d_in[5];
    const float* dt_b   = (const float*)d_in[6];
    const float* A_log  = (const float*)d_in[7];
    const float* Dw     = (const float*)d_in[8];
    const float* out_w  = (const float*)d_in[9];
    float* out = (float*)d_out;

    // Workspace layout (floats). Total = 65,723,648 floats = 262.9 MB
    float* ws  = (float*)d_ws;
    float* xz  = ws;                    // (B,L,512)            12,845,056
    float* xcf = xz  + (size_t)12845056; // (2,B,L,256)         12,845,056
    float* dtv = xcf + (size_t)12845056; // (2,B,L,256)         12,845,056
    float* bc  = dtv + (size_t)12845056; // (2,B,L,32) [B|C]     1,605,632
    float* yg  = bc  + (size_t)1605632;  // (2,B,L,256)         12,845,056
    float* Pg  = yg  + (size_t)12845056; // (4,CCH,256,16)       4,194,304
    float* Hg  = Pg  + (size_t)4194304;
    float* H0  = Hg  + (size_t)4194304;

    // 1) in-proj GEMM: xz = x @ in_w.T   (25088x128 @ 128x512)
    gemm_tn<64,64,32><<<dim3(392,8),256,0,stream>>>(x, nullptr, in_w, xz, NTOK, 512, 128);
    // 2) conv + silu + x-proj + dt-proj (both directions)
    conv_proj<<<dim3(392,2,2),256,0,stream>>>(xz, conv_w, conv_b, x_w, dt_w, dt_b, xcf, dtv, bc);
    // 3) chunked selective scan
    scan_phase1<<<dim3(CCH,2,2),256,0,stream>>>(dtv, xcf, bc, A_log, Pg, Hg);
    scan_combine<<<64,256,0,stream>>>(Pg, Hg, H0);
    scan_phase3<<<dim3(CCH,2,2),256,0,stream>>>(dtv, xcf, bc, A_log, H0, xz, Dw, yg);
    // 4) out-proj GEMM with fwd+bwd sum: out = (yg_f + yg_b) @ out_w.T
    gemm_tn<64,64,32><<<dim3(392,2),256,0,stream>>>(yg, yg + (size_t)6422528, out_w, out, NTOK, DM, 256);
}

// Round 2
// 577.231 us; speedup vs baseline: 1.0345x; 1.0345x over previous
//
#include <hip/hip_runtime.h>
#include <hip/hip_bf16.h>
#include <math.h>

// Problem constants (from reference)
#define LSEQ 12544      // H*W = 112*112
#define NB   2          // batch
#define DM   128        // d_model
#define DI   256        // d_inner
#define DS   16         // d_state
#define RNK  8          // dt_rank
#define NTOK (NB*LSEQ)  // 25088 tokens
#define CCH  256        // scan chunks
#define TCH  49         // tokens per chunk (256*49 = 12544)

__device__ __forceinline__ float sigmoidf_(float x){ return 1.f/(1.f+__expf(-x)); }

// C[M,N] = (A (+A2)) [M,K] @ W[N,K]^T   (all fp32, row-major; M%64==0, N%64==0, K%32==0)
template<int BM,int BN,int BK>
__global__ __launch_bounds__(256)
void gemm_tn(const float* __restrict__ A, const float* __restrict__ A2,
             const float* __restrict__ W, float* __restrict__ C,
             int M, int N, int K)
{
    __shared__ float As[BK][BM+4];
    __shared__ float Ws[BK][BN+4];
    const int tid = threadIdx.x;
    const int tx = tid & 15, ty = tid >> 4;
    const int m0 = blockIdx.x * BM, n0 = blockIdx.y * BN;
    float acc[4][4] = {};
    for (int k0 = 0; k0 < K; k0 += BK) {
        #pragma unroll
        for (int pass = 0; pass < 2; ++pass) {
            int r  = (tid >> 3) + pass*32;
            int c4 = (tid & 7) * 4;
            float4 v = *(const float4*)&A[(size_t)(m0+r)*K + k0 + c4];
            if (A2) {
                float4 v2 = *(const float4*)&A2[(size_t)(m0+r)*K + k0 + c4];
                v.x+=v2.x; v.y+=v2.y; v.z+=v2.z; v.w+=v2.w;
            }
            As[c4+0][r]=v.x; As[c4+1][r]=v.y; As[c4+2][r]=v.z; As[c4+3][r]=v.w;
            float4 w = *(const float4*)&W[(size_t)(n0+r)*K + k0 + c4];
            Ws[c4+0][r]=w.x; Ws[c4+1][r]=w.y; Ws[c4+2][r]=w.z; Ws[c4+3][r]=w.w;
        }
        __syncthreads();
        #pragma unroll
        for (int kk = 0; kk < BK; ++kk) {
            float4 a = *(const float4*)&As[kk][ty*4];
            float4 b = *(const float4*)&Ws[kk][tx*4];
            float av[4]={a.x,a.y,a.z,a.w}, bv[4]={b.x,b.y,b.z,b.w};
            #pragma unroll
            for (int i=0;i<4;i++)
                #pragma unroll
                for (int j=0;j<4;j++)
                    acc[i][j] += av[i]*bv[j];
        }
        __syncthreads();
    }
    #pragma unroll
    for (int i=0;i<4;i++)
        #pragma unroll
        for (int j=0;j<4;j++)
            C[(size_t)(m0+ty*4+i)*N + n0 + tx*4 + j] = acc[i][j];
}

// Fused causal depthwise conv + silu + x-proj mini-GEMM.
// Per block: 64 tokens of one (dir,b). Output dbl[(dir,b,l),40] = xs @ x_w^T.
__global__ __launch_bounds__(256)
void conv_xproj(const float* __restrict__ xz,
                const float* __restrict__ conv_w, const float* __restrict__ conv_b,
                const float* __restrict__ x_w, float* __restrict__ dbl)
{
    __shared__ float xs[64][DI+4];   // padded: ((t*260+k)%32) varies with t -> conflict-free b128
    const int d   = threadIdx.x;
    const int l0  = blockIdx.x * 64;
    const int b   = blockIdx.y, dir = blockIdx.z;
    const float* xzb = xz + (size_t)b * LSEQ * 512;
    const size_t base = ((size_t)(dir*NB + b)) * LSEQ;

    // conv + silu staged into LDS via rolling window over raw rows
    const float w0 = conv_w[d*4+0], w1 = conv_w[d*4+1], w2 = conv_w[d*4+2], w3 = conv_w[d*4+3];
    const float cb = conv_b[d];
    float xm1, xm2, xm3;
    {
        int l1 = l0-1, l2 = l0-2, l3 = l0-3;
        xm1 = (l1 >= 0) ? xzb[(size_t)(dir ? (LSEQ-1-l1) : l1)*512 + d] : 0.f;
        xm2 = (l2 >= 0) ? xzb[(size_t)(dir ? (LSEQ-1-l2) : l2)*512 + d] : 0.f;
        xm3 = (l3 >= 0) ? xzb[(size_t)(dir ? (LSEQ-1-l3) : l3)*512 + d] : 0.f;
    }
    for (int t = 0; t < 64; ++t) {
        const int l = l0 + t;
        const int p = dir ? (LSEQ-1-l) : l;
        const float xr = xzb[(size_t)p*512 + d];
        const float acc = cb + w3*xr + w2*xm1 + w1*xm2 + w0*xm3;
        xm3 = xm2; xm2 = xm1; xm1 = xr;
        xs[t][d] = acc * sigmoidf_(acc);
    }
    __syncthreads();

    // mini-GEMM: 64 tokens x 40 outputs x K=256; 10 accumulators/thread
    const int tx = d & 7, ty = d >> 3;          // ty in 0..31
    float acc[2][5] = {};
    for (int k = 0; k < DI; k += 4) {
        const float4 a0 = *(const float4*)&xs[ty][k];
        const float4 a1 = *(const float4*)&xs[ty+32][k];
        #pragma unroll
        for (int j = 0; j < 5; ++j) {
            const float4 w = *(const float4*)&x_w[(size_t)(tx + 8*j)*DI + k];
            acc[0][j] += a0.x*w.x + a0.y*w.y + a0.z*w.z + a0.w*w.w;
            acc[1][j] += a1.x*w.x + a1.y*w.y + a1.z*w.z + a1.w*w.w;
        }
    }
    #pragma unroll
    for (int j = 0; j < 5; ++j) {
        dbl[(base + l0 + ty   )*40 + tx + 8*j] = acc[0][j];
        dbl[(base + l0 + ty+32)*40 + tx + 8*j] = acc[1][j];
    }
}

// Shared per-token recompute helpers used by both scan phases:
//   conv+silu from rolling window, dt from dbl row (8-dot + softplus).
__device__ __forceinline__ float softplusf_(float x){
    return (x > 20.f) ? x : log1pf(__expf(x));
}

// Phase 1: per-chunk local scan (h0=0) + cumulative decay
__global__ __launch_bounds__(256)
void scan_phase1(const float* __restrict__ xz, const float* __restrict__ dbl,
                 const float* __restrict__ conv_w, const float* __restrict__ conv_b,
                 const float* __restrict__ dt_w, const float* __restrict__ dt_b,
                 const float* __restrict__ A_log,
                 float* __restrict__ Pg, float* __restrict__ Hg)
{
    const int d = threadIdx.x;
    const int c = blockIdx.x, b = blockIdx.y, dir = blockIdx.z;
    float a2[DS];
    #pragma unroll
    for (int n=0;n<DS;n++) a2[n] = -__expf(A_log[d*DS+n]) * 1.4426950408889634f;
    const float w0 = conv_w[d*4+0], w1 = conv_w[d*4+1], w2 = conv_w[d*4+2], w3 = conv_w[d*4+3];
    const float cb = conv_b[d];
    float dw[RNK];
    #pragma unroll
    for (int j=0;j<RNK;j++) dw[j] = dt_w[d*RNK+j];
    const float db = dt_b[d];

    const float* xzb = xz + (size_t)b * LSEQ * 512;
    const size_t base = ((size_t)(dir*NB + b)) * LSEQ;
    const int l0 = c*TCH;
    float xm1, xm2, xm3;
    {
        int l1 = l0-1, l2 = l0-2, l3 = l0-3;
        xm1 = (l1 >= 0) ? xzb[(size_t)(dir ? (LSEQ-1-l1) : l1)*512 + d] : 0.f;
        xm2 = (l2 >= 0) ? xzb[(size_t)(dir ? (LSEQ-1-l2) : l2)*512 + d] : 0.f;
        xm3 = (l3 >= 0) ? xzb[(size_t)(dir ? (LSEQ-1-l3) : l3)*512 + d] : 0.f;
    }
    float h[DS];
    #pragma unroll
    for (int n=0;n<DS;n++) h[n]=0.f;
    float dtsum = 0.f;
    for (int t = 0; t < TCH; ++t) {
        const int l = l0 + t;
        const int p = dir ? (LSEQ-1-l) : l;
        const float xr = xzb[(size_t)p*512 + d];
        const float cv = cb + w3*xr + w2*xm1 + w1*xm2 + w0*xm3;
        xm3 = xm2; xm2 = xm1; xm1 = xr;
        const float xv = cv * sigmoidf_(cv);
        const float* dr = dbl + (base + l)*40;
        float ds_ = db;
        #pragma unroll
        for (int j=0;j<RNK;j++) ds_ += dr[j]*dw[j];
        const float dt = softplusf_(ds_);
        const float4 B0=*(const float4*)(dr+8),  B1=*(const float4*)(dr+12),
                     B2=*(const float4*)(dr+16), B3=*(const float4*)(dr+20);
        const float Bv[16]={B0.x,B0.y,B0.z,B0.w,B1.x,B1.y,B1.z,B1.w,
                            B2.x,B2.y,B2.z,B2.w,B3.x,B3.y,B3.z,B3.w};
        const float u = dt * xv;
        dtsum += dt;
        #pragma unroll
        for (int n=0;n<DS;n++) {
            const float dA = exp2f(dt * a2[n]);
            h[n] = dA*h[n] + u*Bv[n];
        }
    }
    const size_t o = ((size_t)((dir*NB + b)*CCH + c))*(DI*DS) + d*DS;
    #pragma unroll
    for (int n=0;n<DS;n++) { Pg[o+n] = exp2f(dtsum * a2[n]); Hg[o+n] = h[n]; }
}

// Phase 2: sequential combine across chunks (one thread per (dir,b,d,n))
__global__ __launch_bounds__(256)
void scan_combine(const float* __restrict__ Pg, const float* __restrict__ Hg,
                  float* __restrict__ H0)
{
    const int tid = blockIdx.x*blockDim.x + threadIdx.x;  // 16384 threads
    const int dn = tid & 4095;
    const int g  = tid >> 12;            // dir*2+b
    float h = 0.f;
    for (int c = 0; c < CCH; ++c) {
        const size_t o = ((size_t)(g*CCH + c))*(DI*DS) + dn;
        H0[o] = h;
        h = Pg[o]*h + Hg[o];
    }
}

// Phase 3: re-scan with correct initial state, emit gated y
__global__ __launch_bounds__(256)
void scan_phase3(const float* __restrict__ xz, const float* __restrict__ dbl,
                 const float* __restrict__ conv_w, const float* __restrict__ conv_b,
                 const float* __restrict__ dt_w, const float* __restrict__ dt_b,
                 const float* __restrict__ A_log, const float* __restrict__ H0,
                 const float* __restrict__ Dw, float* __restrict__ yg)
{
    const int d = threadIdx.x;
    const int c = blockIdx.x, b = blockIdx.y, dir = blockIdx.z;
    float a2[DS];
    #pragma unroll
    for (int n=0;n<DS;n++) a2[n] = -__expf(A_log[d*DS+n]) * 1.4426950408889634f;
    const float w0 = conv_w[d*4+0], w1 = conv_w[d*4+1], w2 = conv_w[d*4+2], w3 = conv_w[d*4+3];
    const float cb = conv_b[d];
    float dw[RNK];
    #pragma unroll
    for (int j=0;j<RNK;j++) dw[j] = dt_w[d*RNK+j];
    const float db = dt_b[d];
    const float Dv = Dw[d];

    const float* xzb = xz + (size_t)b * LSEQ * 512;
    const size_t base = ((size_t)(dir*NB + b)) * LSEQ;
    const int l0 = c*TCH;
    float xm1, xm2, xm3;
    {
        int l1 = l0-1, l2 = l0-2, l3 = l0-3;
        xm1 = (l1 >= 0) ? xzb[(size_t)(dir ? (LSEQ-1-l1) : l1)*512 + d] : 0.f;
        xm2 = (l2 >= 0) ? xzb[(size_t)(dir ? (LSEQ-1-l2) : l2)*512 + d] : 0.f;
        xm3 = (l3 >= 0) ? xzb[(size_t)(dir ? (LSEQ-1-l3) : l3)*512 + d] : 0.f;
    }
    float h[DS];
    const size_t ho = ((size_t)((dir*NB + b)*CCH + c))*(DI*DS) + d*DS;
    #pragma unroll
    for (int n=0;n<DS;n++) h[n] = H0[ho+n];
    for (int t = 0; t < TCH; ++t) {
        const int l = l0 + t;
        const int p = dir ? (LSEQ-1-l) : l;
        const float xr = xzb[(size_t)p*512 + d];
        const float cv = cb + w3*xr + w2*xm1 + w1*xm2 + w0*xm3;
        xm3 = xm2; xm2 = xm1; xm1 = xr;
        const float xv = cv * sigmoidf_(cv);
        const float* dr = dbl + (base + l)*40;
        float ds_ = db;
        #pragma unroll
        for (int j=0;j<RNK;j++) ds_ += dr[j]*dw[j];
        const float dt = softplusf_(ds_);
        const float4 B0=*(const float4*)(dr+8),  B1=*(const float4*)(dr+12),
                     B2=*(const float4*)(dr+16), B3=*(const float4*)(dr+20);
        const float4 C0=*(const float4*)(dr+24), C1=*(const float4*)(dr+28),
                     C2=*(const float4*)(dr+32), C3=*(const float4*)(dr+36);
        const float Bv[16]={B0.x,B0.y,B0.z,B0.w,B1.x,B1.y,B1.z,B1.w,
                            B2.x,B2.y,B2.z,B2.w,B3.x,B3.y,B3.z,B3.w};
        const float Cv[16]={C0.x,C0.y,C0.z,C0.w,C1.x,C1.y,C1.z,C1.w,
                            C2.x,C2.y,C2.z,C2.w,C3.x,C3.y,C3.z,C3.w};
        const float u = dt*xv;
        float y = 0.f;
        #pragma unroll
        for (int n=0;n<DS;n++){
            const float dA = exp2f(dt*a2[n]);
            h[n] = dA*h[n] + u*Bv[n];
            y += h[n]*Cv[n];
        }
        const float z = xzb[(size_t)p*512 + DI + d];
        yg[(base+p)*DI + d] = (y + xv*Dv) * (z * sigmoidf_(z));
    }
}

extern "C" void kernel_launch(void* const* d_in, const int* in_sizes, int n_in,
                              void* d_out, int out_size, void* d_ws, size_t ws_size,
                              hipStream_t stream)
{
    const float* x      = (const float*)d_in[0];
    const float* in_w   = (const float*)d_in[1];
    const float* conv_w = (const float*)d_in[2];
    const float* conv_b = (const float*)d_in[3];
    const float* x_w    = (const float*)d_in[4];
    const float* dt_w   = (const float*)d_in[5];
    const float* dt_b   = (const float*)d_in[6];
    const float* A_log  = (const float*)d_in[7];
    const float* Dw     = (const float*)d_in[8];
    const float* out_w  = (const float*)d_in[9];
    float* out = (float*)d_out;

    // Workspace layout (floats). Total = 40,280,064 floats = 161.1 MB
    float* ws  = (float*)d_ws;
    float* xz  = ws;                     // (B,L,512)            12,845,056
    float* dbl = xz  + (size_t)12845056; // (2,B,L,40)            2,007,040
    float* yg  = dbl + (size_t)2007040;  // (2,B,L,256)          12,845,056
    float* Pg  = yg  + (size_t)12845056; // (4,CCH,256,16)        4,194,304
    float* Hg  = Pg  + (size_t)4194304;
    float* H0  = Hg  + (size_t)4194304;

    // 1) in-proj GEMM: xz = x @ in_w.T   (25088x128 @ 128x512)
    gemm_tn<64,64,32><<<dim3(392,8),256,0,stream>>>(x, nullptr, in_w, xz, NTOK, 512, 128);
    // 2) fused conv + silu + x-proj (both directions) -> dbl
    conv_xproj<<<dim3(196,2,2),256,0,stream>>>(xz, conv_w, conv_b, x_w, dbl);
    // 3) chunked selective scan (conv + dt recomputed on the fly)
    scan_phase1<<<dim3(CCH,2,2),256,0,stream>>>(xz, dbl, conv_w, conv_b, dt_w, dt_b, A_log, Pg, Hg);
    scan_combine<<<64,256,0,stream>>>(Pg, Hg, H0);
    scan_phase3<<<dim3(CCH,2,2),256,0,stream>>>(xz, dbl, conv_w, conv_b, dt_w, dt_b, A_log, H0, Dw, yg);
    // 4) out-proj GEMM with fwd+bwd sum: out = (yg_f + yg_b) @ out_w.T
    gemm_tn<64,64,32><<<dim3(392,2),256,0,stream>>>(yg, yg + (size_t)6422528, out_w, out, NTOK, DM, 256);
}